// Round 2
// baseline (267.094 us; speedup 1.0000x reference)
//
#include <hip/hip_runtime.h>
#include <hip/hip_bf16.h>

typedef __bf16 bf16x8_t __attribute__((ext_vector_type(8)));
typedef float f32x4_t __attribute__((ext_vector_type(4)));
using bf16 = __hip_bfloat16;

// 13 cubic B-spline basis values (grid 10, k=3, [-2,2]) + mish, written to LDS.
__device__ __forceinline__ void kan_feats_lds(bf16* dst, float x) {
#pragma unroll
  for (int j = 0; j < 13; ++j) dst[j] = __float2bfloat16(0.0f);
  float t = (x + 3.2f) * 2.5f;
  if (t >= 0.0f && t < 16.0f) {
    float tf = floorf(t);
    int c = (int)tf;
    float u = t - tf;
    float um = 1.0f - u;
    float u2 = u * u, u3 = u2 * u;
    const float s6 = 1.0f / 6.0f;
    float w0 = um * um * um * s6;
    float w1 = (3.0f * u3 - 6.0f * u2 + 4.0f) * s6;
    float w2 = (-3.0f * u3 + 3.0f * u2 + 3.0f * u + 1.0f) * s6;
    float w3 = u3 * s6;
    int j0 = c - 3;
    if (j0 >= 0)               dst[j0]     = __float2bfloat16(w0);
    if (j0 >= -1 && j0 <= 11)  dst[j0 + 1] = __float2bfloat16(w1);
    if (j0 >= -2 && j0 <= 10)  dst[j0 + 2] = __float2bfloat16(w2);
    if (j0 <= 9)               dst[j0 + 3] = __float2bfloat16(w3);
  }
  float sp = (x > 20.0f) ? x : log1pf(expf(x));
  dst[13] = __float2bfloat16(x * tanhf(sp));
}

// Wt[o][i*14+r] = r<13 ? coef[i][o][r]*sp[i][o] : sb[i][o]; zero-padded.
__global__ __launch_bounds__(256) void prep_w(
    const float* __restrict__ coef, const float* __restrict__ sb,
    const float* __restrict__ sp, bf16* __restrict__ Wt,
    int in, int out, int outPad, int Kpad) {
  const int idx = blockIdx.x * 256 + threadIdx.x;
  if (idx >= outPad * Kpad) return;
  const int o = idx / Kpad;
  const int kk = idx - o * Kpad;
  float v = 0.0f;
  if (o < out && kk < in * 14) {
    const int i = kk / 14;
    const int r = kk - i * 14;
    v = (r < 13) ? coef[((size_t)i * out + o) * 13 + r] * sp[(size_t)i * out + o]
                 : sb[(size_t)i * out + o];
  }
  Wt[(size_t)o * Kpad + kk] = __float2bfloat16(v);
}

// One block per image: 4x4 avg-pool 28x28 -> 49, then basis+mish -> A1 row (704 bf16).
__global__ __launch_bounds__(256) void pool_basis1(const float* __restrict__ x,
                                                   bf16* __restrict__ A1) {
  __shared__ __align__(16) float xs[784];
  __shared__ __align__(16) bf16 arow[704];
  const int b = blockIdx.x, t = threadIdx.x;
  if (t < 196) *(float4*)(&xs[t * 4]) = *(const float4*)(x + (size_t)b * 784 + t * 4);
  __syncthreads();
  if (t < 49) {
    const int oh = t / 7, ow = t % 7;
    float s = 0.f;
#pragma unroll
    for (int r = 0; r < 4; ++r)
#pragma unroll
      for (int c = 0; c < 4; ++c) s += xs[(oh * 4 + r) * 28 + ow * 4 + c];
    kan_feats_lds(&arow[t * 14], s * (1.0f / 16.0f));
  } else if (t < 67) {
    arow[686 + (t - 49)] = __float2bfloat16(0.0f);  // K pad 686..703
  }
  __syncthreads();
  if (t < 88) ((uint4*)((char*)A1 + (size_t)b * 1408))[t] = ((const uint4*)arow)[t];
}

// H (fp32, B x 256) -> augmented A (bf16, B x 3584), one block per row.
__global__ __launch_bounds__(256) void basis23(const float* __restrict__ Hin,
                                               bf16* __restrict__ Aout) {
  __shared__ __align__(16) bf16 arow[3584];
  const int b = blockIdx.x, t = threadIdx.x;
  kan_feats_lds(&arow[t * 14], Hin[(size_t)b * 256 + t]);
  __syncthreads();
  uint4* dst = (uint4*)((char*)Aout + (size_t)b * 7168);
  const uint4* src = (const uint4*)arow;
  dst[t] = src[t];
  if (t < 192) dst[256 + t] = src[256 + t];
}

// Barrier-free register-direct GEMM: C[m][n] = sum_k A[m][k]*Wt[n][k] + bias[n].
// 64x64 block (4 waves, each 32x32). MFMA fragments loaded straight from
// row-major global (lane lr -> row, quad*8 -> k offset, 16B each): no LDS,
// no __syncthreads -> compiler pipelines loads with vmcnt(N).
template <int K>
__global__ __launch_bounds__(256) void gemm64r(
    const bf16* __restrict__ A, const bf16* __restrict__ Wt,
    const float* __restrict__ bias, float* __restrict__ H) {
  const int t = threadIdx.x;
  const int wv = t >> 6, lane = t & 63, quad = lane >> 4, lr = lane & 15;
  const int m0 = blockIdx.x * 64 + (wv & 1) * 32;
  const int n0 = blockIdx.y * 64 + (wv >> 1) * 32;
  const bf16* pa0 = A + (size_t)(m0 + lr) * K + quad * 8;
  const bf16* pa1 = pa0 + (size_t)16 * K;
  const bf16* pb0 = Wt + (size_t)(n0 + lr) * K + quad * 8;
  const bf16* pb1 = pb0 + (size_t)16 * K;
  f32x4_t acc00 = {0.f, 0.f, 0.f, 0.f}, acc01 = acc00, acc10 = acc00, acc11 = acc00;
#pragma unroll 4
  for (int k0 = 0; k0 < K; k0 += 32) {
    bf16x8_t a0 = *(const bf16x8_t*)(pa0 + k0);
    bf16x8_t a1 = *(const bf16x8_t*)(pa1 + k0);
    bf16x8_t b0 = *(const bf16x8_t*)(pb0 + k0);
    bf16x8_t b1 = *(const bf16x8_t*)(pb1 + k0);
    acc00 = __builtin_amdgcn_mfma_f32_16x16x32_bf16(a0, b0, acc00, 0, 0, 0);
    acc01 = __builtin_amdgcn_mfma_f32_16x16x32_bf16(a0, b1, acc01, 0, 0, 0);
    acc10 = __builtin_amdgcn_mfma_f32_16x16x32_bf16(a1, b0, acc10, 0, 0, 0);
    acc11 = __builtin_amdgcn_mfma_f32_16x16x32_bf16(a1, b1, acc11, 0, 0, 0);
  }
  const int cb = n0 + lr;
  const float bn0 = bias[cb];
  const float bn1 = bias[cb + 16];
#pragma unroll
  for (int r = 0; r < 4; ++r) {
    const size_t row = (size_t)(m0 + quad * 4 + r);
    H[row * 256 + cb] = acc00[r] + bn0;
    H[row * 256 + cb + 16] = acc01[r] + bn1;
    H[(row + 16) * 256 + cb] = acc10[r] + bn0;
    H[(row + 16) * 256 + cb + 16] = acc11[r] + bn1;
  }
}

// Layer-3 GEMM, barrier-free: N=16 (10 real), split-K over blockIdx.y (8x448).
// partials layout [kc][n][m] so the reducer reads coalesced.
__global__ __launch_bounds__(256) void gemm3kr(
    const bf16* __restrict__ A, const bf16* __restrict__ Wt,
    float* __restrict__ part) {
  constexpr int K = 3584;
  const int t = threadIdx.x;
  const int wv = t >> 6, lane = t & 63, quad = lane >> 4, lr = lane & 15;
  const int m0 = blockIdx.x * 64 + wv * 16;
  const int kc = blockIdx.y;
  const int kbeg = kc * 448;
  const bf16* pa = A + (size_t)(m0 + lr) * K + kbeg + quad * 8;
  const bf16* pb = Wt + (size_t)lr * K + kbeg + quad * 8;
  f32x4_t acc = {0.f, 0.f, 0.f, 0.f};
#pragma unroll 7
  for (int k0 = 0; k0 < 448; k0 += 32) {
    bf16x8_t a = *(const bf16x8_t*)(pa + k0);
    bf16x8_t b = *(const bf16x8_t*)(pb + k0);
    acc = __builtin_amdgcn_mfma_f32_16x16x32_bf16(a, b, acc, 0, 0, 0);
  }
#pragma unroll
  for (int r = 0; r < 4; ++r)
    part[(size_t)kc * 131072 + (size_t)lr * 8192 + (m0 + quad * 4 + r)] = acc[r];
}

// Reduce split-K partials + bias, log_softmax over 10 classes.
__global__ __launch_bounds__(256) void lsm(const float* __restrict__ part,
                                           const float* __restrict__ b3,
                                           float* __restrict__ out) {
  const int row = blockIdx.x * 256 + threadIdx.x;
  float v[10];
#pragma unroll
  for (int o = 0; o < 10; ++o) {
    float s = b3[o];
#pragma unroll
    for (int kc = 0; kc < 8; ++kc) s += part[(size_t)kc * 131072 + (size_t)o * 8192 + row];
    v[o] = s;
  }
  float m = v[0];
#pragma unroll
  for (int o = 1; o < 10; ++o) m = fmaxf(m, v[o]);
  float se = 0.f;
#pragma unroll
  for (int o = 0; o < 10; ++o) se += expf(v[o] - m);
  const float l = m + logf(se);
#pragma unroll
  for (int o = 0; o < 10; ++o) out[(size_t)row * 10 + o] = v[o] - l;
}

extern "C" void kernel_launch(void* const* d_in, const int* in_sizes, int n_in,
                              void* d_out, int out_size, void* d_ws, size_t ws_size,
                              hipStream_t stream) {
  const float* x = (const float*)d_in[0];
  const float* coef1 = (const float*)d_in[1];
  const float* sb1 = (const float*)d_in[2];
  const float* sp1 = (const float*)d_in[3];
  const float* b1 = (const float*)d_in[4];
  const float* coef2 = (const float*)d_in[5];
  const float* sb2 = (const float*)d_in[6];
  const float* sp2 = (const float*)d_in[7];
  const float* b2 = (const float*)d_in[8];
  const float* coef3 = (const float*)d_in[9];
  const float* sb3 = (const float*)d_in[10];
  const float* sp3 = (const float*)d_in[11];
  const float* b3 = (const float*)d_in[12];
  float* out = (float*)d_out;

  char* ws = (char*)d_ws;
  size_t off = 0;
  bf16* A1 = (bf16*)(ws + off);  off += 11534336;   // 8192*704*2
  bf16* W1t = (bf16*)(ws + off); off += 360448;     // 256*704*2
  float* H1 = (float*)(ws + off); off += 8388608;   // 8192*256*4
  bf16* A2 = (bf16*)(ws + off);  off += 58720256;   // 8192*3584*2 (reused for A3)
  bf16* W2t = (bf16*)(ws + off); off += 1835008;    // 256*3584*2
  float* H2 = (float*)(ws + off); off += 8388608;
  bf16* W3t = (bf16*)(ws + off); off += 114688;     // 16*3584*2
  float* part = (float*)(ws + off); off += 4194304; // 8*16*8192*4

  prep_w<<<704, 256, 0, stream>>>(coef1, sb1, sp1, W1t, 49, 256, 256, 704);
  prep_w<<<3584, 256, 0, stream>>>(coef2, sb2, sp2, W2t, 256, 256, 256, 3584);
  prep_w<<<224, 256, 0, stream>>>(coef3, sb3, sp3, W3t, 256, 10, 16, 3584);

  pool_basis1<<<8192, 256, 0, stream>>>(x, A1);
  gemm64r<704><<<dim3(128, 4), 256, 0, stream>>>(A1, W1t, b1, H1);
  basis23<<<8192, 256, 0, stream>>>(H1, A2);
  gemm64r<3584><<<dim3(128, 4), 256, 0, stream>>>(A2, W2t, b2, H2);
  basis23<<<8192, 256, 0, stream>>>(H2, A2);
  gemm3kr<<<dim3(128, 8), 256, 0, stream>>>(A2, W3t, part);
  lsm<<<32, 256, 0, stream>>>(part, b3, out);
}

// Round 3
// 191.806 us; speedup vs baseline: 1.3925x; 1.3925x over previous
//
#include <hip/hip_runtime.h>
#include <hip/hip_bf16.h>

typedef __bf16 bf16x8_t __attribute__((ext_vector_type(8)));
typedef float f32x4_t __attribute__((ext_vector_type(4)));
using bf16 = __hip_bfloat16;

#define ASG __attribute__((address_space(1)))
#define ASL __attribute__((address_space(3)))

__device__ __forceinline__ void gld_lds16(const void* g, void* l) {
  // lane i of the wave lands at (wave-uniform lds base) + i*16 bytes.
  __builtin_amdgcn_global_load_lds((ASG void*)const_cast<void*>(g),
                                   (ASL void*)l, 16, 0, 0);
}

// 13 cubic B-spline basis values (grid 10, k=3, [-2,2]) + mish -> dst[0..13].
__device__ __forceinline__ void kan_feats_lds(bf16* dst, float x) {
#pragma unroll
  for (int j = 0; j < 13; ++j) dst[j] = __float2bfloat16(0.0f);
  float t = (x + 3.2f) * 2.5f;
  if (t >= 0.0f && t < 16.0f) {
    float tf = floorf(t);
    int c = (int)tf;
    float u = t - tf;
    float um = 1.0f - u;
    float u2 = u * u, u3 = u2 * u;
    const float s6 = 1.0f / 6.0f;
    float w0 = um * um * um * s6;
    float w1 = (3.0f * u3 - 6.0f * u2 + 4.0f) * s6;
    float w2 = (-3.0f * u3 + 3.0f * u2 + 3.0f * u + 1.0f) * s6;
    float w3 = u3 * s6;
    int j0 = c - 3;
    if (j0 >= 0)               dst[j0]     = __float2bfloat16(w0);
    if (j0 >= -1 && j0 <= 11)  dst[j0 + 1] = __float2bfloat16(w1);
    if (j0 >= -2 && j0 <= 10)  dst[j0 + 2] = __float2bfloat16(w2);
    if (j0 <= 9)               dst[j0 + 3] = __float2bfloat16(w3);
  }
  float sp = (x > 20.0f) ? x : log1pf(expf(x));
  dst[13] = __float2bfloat16(x * tanhf(sp));
}

// Wt[o][i*14+r] = r<13 ? coef[i][o][r]*sp[i][o] : sb[i][o]; zero-padded.
__global__ __launch_bounds__(256) void prep_w(
    const float* __restrict__ coef, const float* __restrict__ sb,
    const float* __restrict__ sp, bf16* __restrict__ Wt,
    int in, int out, int outPad, int Kpad) {
  const int idx = blockIdx.x * 256 + threadIdx.x;
  if (idx >= outPad * Kpad) return;
  const int o = idx / Kpad;
  const int kk = idx - o * Kpad;
  float v = 0.0f;
  if (o < out && kk < in * 14) {
    const int i = kk / 14;
    const int r = kk - i * 14;
    v = (r < 13) ? coef[((size_t)i * out + o) * 13 + r] * sp[(size_t)i * out + o]
                 : sb[(size_t)i * out + o];
  }
  Wt[(size_t)o * Kpad + kk] = __float2bfloat16(v);
}

// One block per image: 4x4 avg-pool 28x28 -> 49, then basis+mish -> A1 row (704 bf16).
__global__ __launch_bounds__(256) void pool_basis1(const float* __restrict__ x,
                                                   bf16* __restrict__ A1) {
  __shared__ __align__(16) float xs[784];
  __shared__ __align__(16) bf16 arow[704];
  const int b = blockIdx.x, t = threadIdx.x;
  if (t < 196) *(float4*)(&xs[t * 4]) = *(const float4*)(x + (size_t)b * 784 + t * 4);
  __syncthreads();
  if (t < 49) {
    const int oh = t / 7, ow = t % 7;
    float s = 0.f;
#pragma unroll
    for (int r = 0; r < 4; ++r)
#pragma unroll
      for (int c = 0; c < 4; ++c) s += xs[(oh * 4 + r) * 28 + ow * 4 + c];
    kan_feats_lds(&arow[t * 14], s * (1.0f / 16.0f));
  } else if (t < 67) {
    arow[686 + (t - 49)] = __float2bfloat16(0.0f);  // K pad 686..703
  }
  __syncthreads();
  if (t < 88) ((uint4*)((char*)A1 + (size_t)b * 1408))[t] = ((const uint4*)arow)[t];
}

// h = Ha+Hb+bias (split-K partial sum), then basis+mish -> A row (3584 bf16).
__global__ __launch_bounds__(256) void basis23s(
    const float* __restrict__ Ha, const float* __restrict__ Hb,
    const float* __restrict__ bias, bf16* __restrict__ Aout) {
  __shared__ __align__(16) bf16 arow[3584];
  const int b = blockIdx.x, t = threadIdx.x;
  const float h = Ha[(size_t)b * 256 + t] + Hb[(size_t)b * 256 + t] + bias[t];
  kan_feats_lds(&arow[t * 14], h);
  __syncthreads();
  uint4* dst = (uint4*)((char*)Aout + (size_t)b * 7168);
  const uint4* src = (const uint4*)arow;
  dst[t] = src[t];
  if (t < 192) dst[256 + t] = src[256 + t];
}

// LDS-staged GEMM, BK=64, XOR-swizzled LDS to kill ds_read_b128 bank conflicts.
// Split-K over blockIdx.z (2 chunks); partials to Hpart[z]. Grid (ncol, mrow, 2),
// col fastest so same-A blocks are temporally adjacent (L2/L3 locality).
// LDS layout: byte addr row*128 + slot*16, slot holds global chunk slot^(row&7).
template <int K, int KSPLIT>
__global__ __launch_bounds__(256) void gemm64s(
    const bf16* __restrict__ A, const bf16* __restrict__ Wt,
    float* __restrict__ Hpart) {
  __shared__ __align__(16) bf16 As[64 * 64];
  __shared__ __align__(16) bf16 Bs[64 * 64];
  const int t = threadIdx.x;
  const int wv = t >> 6, lane = t & 63, quad = lane >> 4, lr = lane & 15;
  const int n0 = blockIdx.x * 64;
  const int m0 = blockIdx.y * 64;
  const int kbeg = blockIdx.z * KSPLIT;
  const int kend = blockIdx.z ? K : KSPLIT;
  // staging: wave wv round r stages rows r*32 + 8*wv .. +7 (8 rows x 8 slots x 16B)
  const int srow0 = lane >> 3;        // row within 8-row group
  const int cg = (lane & 7) ^ srow0;  // global 16B-chunk index (XOR swizzle)
  const bf16* gA0 = A + (size_t)(m0 + 8 * wv + srow0) * K + cg * 8;
  const bf16* gA1 = A + (size_t)(m0 + 32 + 8 * wv + srow0) * K + cg * 8;
  const bf16* gB0 = Wt + (size_t)(n0 + 8 * wv + srow0) * K + cg * 8;
  const bf16* gB1 = Wt + (size_t)(n0 + 32 + 8 * wv + srow0) * K + cg * 8;
  char* const lA = (char*)As + wv * 1024;
  char* const lB = (char*)Bs + wv * 1024;
  const int wm = (wv & 1) * 32, wn = (wv >> 1) * 32;
  const int swz = lr & 7;
  f32x4_t acc00 = {0.f, 0.f, 0.f, 0.f}, acc01 = acc00, acc10 = acc00, acc11 = acc00;
  for (int k0 = kbeg; k0 < kend; k0 += 64) {
    gld_lds16(gA0 + k0, lA);
    gld_lds16(gA1 + k0, lA + 4096);
    gld_lds16(gB0 + k0, lB);
    gld_lds16(gB1 + k0, lB + 4096);
    __syncthreads();
#pragma unroll
    for (int s = 0; s < 2; ++s) {
      const int co = ((s * 4 + quad) ^ swz) * 16;
      bf16x8_t a0 = *(const bf16x8_t*)((char*)As + (wm + lr) * 128 + co);
      bf16x8_t a1 = *(const bf16x8_t*)((char*)As + (wm + 16 + lr) * 128 + co);
      bf16x8_t b0 = *(const bf16x8_t*)((char*)Bs + (wn + lr) * 128 + co);
      bf16x8_t b1 = *(const bf16x8_t*)((char*)Bs + (wn + 16 + lr) * 128 + co);
      acc00 = __builtin_amdgcn_mfma_f32_16x16x32_bf16(a0, b0, acc00, 0, 0, 0);
      acc01 = __builtin_amdgcn_mfma_f32_16x16x32_bf16(a0, b1, acc01, 0, 0, 0);
      acc10 = __builtin_amdgcn_mfma_f32_16x16x32_bf16(a1, b0, acc10, 0, 0, 0);
      acc11 = __builtin_amdgcn_mfma_f32_16x16x32_bf16(a1, b1, acc11, 0, 0, 0);
    }
    __syncthreads();
  }
  float* Hp = Hpart + (size_t)blockIdx.z * (8192 * 256);
  const int cb = n0 + wn + lr;
#pragma unroll
  for (int r = 0; r < 4; ++r) {
    const size_t row = (size_t)(m0 + wm + quad * 4 + r);
    Hp[row * 256 + cb] = acc00[r];
    Hp[row * 256 + cb + 16] = acc01[r];
    Hp[(row + 16) * 256 + cb] = acc10[r];
    Hp[(row + 16) * 256 + cb + 16] = acc11[r];
  }
}

// Layer-3: 64xM tile, N=16, split-K over blockIdx.y (8 x 448), staged+swizzled.
// partials layout [kc][n][m] so the reducer reads coalesced.
__global__ __launch_bounds__(256) void gemm3ks(
    const bf16* __restrict__ A, const bf16* __restrict__ Wt,
    float* __restrict__ part) {
  constexpr int K = 3584;
  __shared__ __align__(16) bf16 As[64 * 64];
  __shared__ __align__(16) bf16 Bs[16 * 64];
  const int t = threadIdx.x;
  const int wv = t >> 6, lane = t & 63, quad = lane >> 4, lr = lane & 15;
  const int m0 = blockIdx.x * 64;
  const int kc = blockIdx.y;
  const int kbeg = kc * 448;
  const int srow0 = lane >> 3;
  const int cg = (lane & 7) ^ srow0;
  const bf16* gA0 = A + (size_t)(m0 + 8 * wv + srow0) * K + cg * 8;
  const bf16* gA1 = A + (size_t)(m0 + 32 + 8 * wv + srow0) * K + cg * 8;
  const bf16* gB = Wt + (size_t)(8 * wv + srow0) * K + cg * 8;  // rows 0..15, wv<2
  char* const lA = (char*)As + wv * 1024;
  char* const lB = (char*)Bs + wv * 1024;
  const int swz = lr & 7;
  f32x4_t acc = {0.f, 0.f, 0.f, 0.f};
  for (int k0 = kbeg; k0 < kbeg + 448; k0 += 64) {
    gld_lds16(gA0 + k0, lA);
    gld_lds16(gA1 + k0, lA + 4096);
    if (wv < 2) gld_lds16(gB + k0, lB);
    __syncthreads();
#pragma unroll
    for (int s = 0; s < 2; ++s) {
      const int co = ((s * 4 + quad) ^ swz) * 16;
      bf16x8_t a = *(const bf16x8_t*)((char*)As + (wv * 16 + lr) * 128 + co);
      bf16x8_t b = *(const bf16x8_t*)((char*)Bs + lr * 128 + co);
      acc = __builtin_amdgcn_mfma_f32_16x16x32_bf16(a, b, acc, 0, 0, 0);
    }
    __syncthreads();
  }
#pragma unroll
  for (int r = 0; r < 4; ++r)
    part[(size_t)kc * 131072 + (size_t)lr * 8192 + (m0 + wv * 16 + quad * 4 + r)] = acc[r];
}

// Reduce split-K partials + bias, log_softmax over 10 classes.
__global__ __launch_bounds__(256) void lsm(const float* __restrict__ part,
                                           const float* __restrict__ b3,
                                           float* __restrict__ out) {
  const int row = blockIdx.x * 256 + threadIdx.x;
  float v[10];
#pragma unroll
  for (int o = 0; o < 10; ++o) {
    float s = b3[o];
#pragma unroll
    for (int kc = 0; kc < 8; ++kc) s += part[(size_t)kc * 131072 + (size_t)o * 8192 + row];
    v[o] = s;
  }
  float m = v[0];
#pragma unroll
  for (int o = 1; o < 10; ++o) m = fmaxf(m, v[o]);
  float se = 0.f;
#pragma unroll
  for (int o = 0; o < 10; ++o) se += expf(v[o] - m);
  const float l = m + logf(se);
#pragma unroll
  for (int o = 0; o < 10; ++o) out[(size_t)row * 10 + o] = v[o] - l;
}

extern "C" void kernel_launch(void* const* d_in, const int* in_sizes, int n_in,
                              void* d_out, int out_size, void* d_ws, size_t ws_size,
                              hipStream_t stream) {
  const float* x = (const float*)d_in[0];
  const float* coef1 = (const float*)d_in[1];
  const float* sb1 = (const float*)d_in[2];
  const float* sp1 = (const float*)d_in[3];
  const float* b1 = (const float*)d_in[4];
  const float* coef2 = (const float*)d_in[5];
  const float* sb2 = (const float*)d_in[6];
  const float* sp2 = (const float*)d_in[7];
  const float* b2 = (const float*)d_in[8];
  const float* coef3 = (const float*)d_in[9];
  const float* sb3 = (const float*)d_in[10];
  const float* sp3 = (const float*)d_in[11];
  const float* b3 = (const float*)d_in[12];
  float* out = (float*)d_out;

  char* ws = (char*)d_ws;
  size_t off = 0;
  bf16* A1 = (bf16*)(ws + off);   off += 11534336;   // 8192*704*2
  bf16* W1t = (bf16*)(ws + off);  off += 360448;     // 256*704*2
  float* H1p = (float*)(ws + off); off += 16777216;  // 2 x 8192*256*4 (split-K partials)
  bf16* A2 = (bf16*)(ws + off);   off += 58720256;   // 8192*3584*2 (reused for A3)
  bf16* W2t = (bf16*)(ws + off);  off += 1835008;    // 256*3584*2
  bf16* W3t = (bf16*)(ws + off);  off += 114688;     // 16*3584*2
  float* part = (float*)(ws + off); off += 4194304;  // 8*16*8192*4
  // H2 partials alias the A1/W1t/H1p region (all dead before gemm2 writes them).
  float* H2p = (float*)ws;                           // 2 x 8192*256*4 = 16.78MB

  prep_w<<<704, 256, 0, stream>>>(coef1, sb1, sp1, W1t, 49, 256, 256, 704);
  prep_w<<<3584, 256, 0, stream>>>(coef2, sb2, sp2, W2t, 256, 256, 256, 3584);
  prep_w<<<224, 256, 0, stream>>>(coef3, sb3, sp3, W3t, 256, 10, 16, 3584);

  pool_basis1<<<8192, 256, 0, stream>>>(x, A1);
  gemm64s<704, 384><<<dim3(4, 128, 2), 256, 0, stream>>>(A1, W1t, H1p);
  basis23s<<<8192, 256, 0, stream>>>(H1p, H1p + 8192 * 256, b1, A2);
  gemm64s<3584, 1792><<<dim3(4, 128, 2), 256, 0, stream>>>(A2, W2t, H2p);
  basis23s<<<8192, 256, 0, stream>>>(H2p, H2p + 8192 * 256, b2, A2);
  gemm3ks<<<dim3(128, 8), 256, 0, stream>>>(A2, W3t, part);
  lsm<<<32, 256, 0, stream>>>(part, b3, out);
}